// Round 1
// baseline (399.764 us; speedup 1.0000x reference)
//
#include <hip/hip_runtime.h>
#include <math.h>

#define NBLEND 24
#define HDIM 128
#define MAX_STEPS 10
#define CVG_T 1e-5f
#define DVG_T 1.0f
#define EPS_B 1e-6f

__device__ __forceinline__ float softplus_f(float x) {
    // jax.nn.softplus(x) = max(x,0) + log1p(exp(-|x|)), numerically stable
    float e = __expf(-fabsf(x));
    return fmaxf(x, 0.0f) + __logf(1.0f + e);
}

// One g(x) evaluation for a single point (one thread).
// Weights are wave-uniform -> scalar loads. acc[] indexing is fully static.
template<bool TRANS>
__device__ __forceinline__ void eval_g(
    const float* __restrict__ W0, const float* __restrict__ b0,
    const float* __restrict__ W1, const float* __restrict__ b1,
    const float* __restrict__ W2, const float* __restrict__ b2,
    const float* __restrict__ tfs,
    float x0, float x1, float x2,
    float xd0, float xd1, float xd2,
    float& g0, float& g1, float& g2)
{
    float acc[HDIM];
    #pragma unroll
    for (int k = 0; k < HDIM; ++k) acc[k] = b1[k];

    // fused: h0[j] computed on the fly, rank-1 accumulated into acc (pre-act h1)
    #pragma unroll 2
    for (int j = 0; j < HDIM; ++j) {
        float z = fmaf(x0, W0[j],
                  fmaf(x1, W0[HDIM + j],
                  fmaf(x2, W0[2 * HDIM + j], b0[j])));
        float h = softplus_f(z);
        const float* __restrict__ w1r = W1 + j * HDIM;
        #pragma unroll
        for (int k = 0; k < HDIM; ++k) acc[k] = fmaf(h, w1r[k], acc[k]);
    }
    #pragma unroll
    for (int k = 0; k < HDIM; ++k) acc[k] = softplus_f(acc[k]);

    // logits -> online softmax, accumulating the blended 3x4 transform T
    float M = -3.0e38f, S = 0.0f;
    float T[12];
    #pragma unroll
    for (int t = 0; t < 12; ++t) T[t] = 0.0f;

    for (int m = 0; m < NBLEND; ++m) {
        float lg = b2[m];
        if (TRANS) {
            const float* __restrict__ w2r = W2 + m * HDIM;  // W2 transposed (NB,H)
            #pragma unroll
            for (int k = 0; k < HDIM; ++k) lg = fmaf(acc[k], w2r[k], lg);
        } else {
            #pragma unroll
            for (int k = 0; k < HDIM; ++k) lg = fmaf(acc[k], W2[k * NBLEND + m], lg);
        }
        float Mn = fmaxf(M, lg);
        float c = __expf(M - Mn);   // rescale factor for previous accumulation
        float e = __expf(lg - Mn);
        S = fmaf(S, c, e);
        const float* __restrict__ tf = tfs + m * 12;
        #pragma unroll
        for (int t = 0; t < 12; ++t) T[t] = fmaf(T[t], c, e * tf[t]);
        M = Mn;
    }
    float inv = 1.0f / S;
    g0 = inv * fmaf(T[0], x0, fmaf(T[1],  x1, fmaf(T[2],  x2, T[3])))  - xd0;
    g1 = inv * fmaf(T[4], x0, fmaf(T[5],  x1, fmaf(T[6],  x2, T[7])))  - xd1;
    g2 = inv * fmaf(T[8], x0, fmaf(T[9],  x1, fmaf(T[10], x2, T[11]))) - xd2;
}

__global__ void transpose_w2_kernel(const float* __restrict__ W2,
                                    float* __restrict__ W2T) {
    int i = blockIdx.x * blockDim.x + threadIdx.x;   // i over H*NB
    if (i < HDIM * NBLEND) {
        int k = i / NBLEND, m = i % NBLEND;
        W2T[m * HDIM + k] = W2[i];
    }
}

template<bool TRANS>
__global__ __launch_bounds__(256, 2)
void broyden_kernel(const float* __restrict__ xd_p,
                    const float* __restrict__ x_init,
                    const float* __restrict__ Jinv_init,
                    const float* __restrict__ tfs,
                    const float* __restrict__ W0, const float* __restrict__ b0,
                    const float* __restrict__ W1, const float* __restrict__ b1,
                    const float* __restrict__ W2, const float* __restrict__ b2,
                    float* __restrict__ out, int N)
{
    int n = blockIdx.x * blockDim.x + threadIdx.x;
    if (n >= N) return;

    float xd0 = xd_p[n * 3 + 0], xd1 = xd_p[n * 3 + 1], xd2 = xd_p[n * 3 + 2];
    float x0 = x_init[n * 3 + 0], x1 = x_init[n * 3 + 1], x2 = x_init[n * 3 + 2];
    float J[9];
    #pragma unroll
    for (int a = 0; a < 9; ++a) J[a] = Jinv_init[n * 9 + a];

    float g0, g1, g2;
    eval_g<TRANS>(W0, b0, W1, b1, W2, b2, tfs, x0, x1, x2, xd0, xd1, xd2, g0, g1, g2);

    // update = -Jinv @ gx
    float u0 = -(fmaf(J[0], g0, fmaf(J[1], g1, J[2] * g2)));
    float u1 = -(fmaf(J[3], g0, fmaf(J[4], g1, J[5] * g2)));
    float u2 = -(fmaf(J[6], g0, fmaf(J[7], g1, J[8] * g2)));

    float gn_opt = sqrtf(g0 * g0 + g1 * g1 + g2 * g2);
    float xo0 = x0, xo1 = x1, xo2 = x2;
    bool ids = true;   // reference initializes ids = ones(bool)

    for (int step = 0; step < MAX_STEPS; ++step) {
        if (__ballot(ids) == 0ull) break;   // whole wave frozen -> outputs final
        if (ids) {
            float dx0 = u0, dx1 = u1, dx2 = u2;
            x0 += dx0; x1 += dx1; x2 += dx2;

            float ng0, ng1, ng2;
            eval_g<TRANS>(W0, b0, W1, b1, W2, b2, tfs, x0, x1, x2, xd0, xd1, xd2,
                          ng0, ng1, ng2);
            float dg0 = ng0 - g0, dg1 = ng1 - g1, dg2 = ng2 - g2;
            g0 = ng0; g1 = ng1; g2 = ng2;

            float gn = sqrtf(g0 * g0 + g1 * g1 + g2 * g2);
            bool better = gn < gn_opt;           // false for NaN, matches jnp.where
            if (better) { gn_opt = gn; xo0 = x0; xo1 = x1; xo2 = x2; }
            bool ids_new = (gn_opt > CVG_T) && (gn < DVG_T);

            // vT = dx^T @ Jinv   (row vector)
            float vT0 = fmaf(dx0, J[0], fmaf(dx1, J[3], dx2 * J[6]));
            float vT1 = fmaf(dx0, J[1], fmaf(dx1, J[4], dx2 * J[7]));
            float vT2 = fmaf(dx0, J[2], fmaf(dx1, J[5], dx2 * J[8]));
            // a = dx - Jinv @ dgx
            float a0 = dx0 - fmaf(J[0], dg0, fmaf(J[1], dg1, J[2] * dg2));
            float a1 = dx1 - fmaf(J[3], dg0, fmaf(J[4], dg1, J[5] * dg2));
            float a2 = dx2 - fmaf(J[6], dg0, fmaf(J[7], dg1, J[8] * dg2));
            // b = vT @ dgx (scalar), signed-eps guard
            float bb = fmaf(vT0, dg0, fmaf(vT1, dg1, vT2 * dg2));
            bb += (bb >= 0.0f) ? EPS_B : -EPS_B;
            float iu0 = a0 / bb, iu1 = a1 / bb, iu2 = a2 / bb;

            if (ids_new) {   // Jinv += u (outer) vT, masked by NEW ids
                J[0] = fmaf(iu0, vT0, J[0]); J[1] = fmaf(iu0, vT1, J[1]); J[2] = fmaf(iu0, vT2, J[2]);
                J[3] = fmaf(iu1, vT0, J[3]); J[4] = fmaf(iu1, vT1, J[4]); J[5] = fmaf(iu1, vT2, J[5]);
                J[6] = fmaf(iu2, vT0, J[6]); J[7] = fmaf(iu2, vT1, J[7]); J[8] = fmaf(iu2, vT2, J[8]);
            }
            // update = -Jinv @ gx (recompute; unused next step if ids_new false)
            u0 = -(fmaf(J[0], g0, fmaf(J[1], g1, J[2] * g2)));
            u1 = -(fmaf(J[3], g0, fmaf(J[4], g1, J[5] * g2)));
            u2 = -(fmaf(J[6], g0, fmaf(J[7], g1, J[8] * g2)));
            ids = ids_new;
        }
    }

    // outputs: x_opt (N,3,1) | gn_opt (N) | valid (N) as 0.0/1.0
    out[n * 3 + 0] = xo0;
    out[n * 3 + 1] = xo1;
    out[n * 3 + 2] = xo2;
    out[3 * N + n] = gn_opt;
    out[4 * N + n] = (gn_opt < CVG_T) ? 1.0f : 0.0f;
}

extern "C" void kernel_launch(void* const* d_in, const int* in_sizes, int n_in,
                              void* d_out, int out_size, void* d_ws, size_t ws_size,
                              hipStream_t stream) {
    const float* xd     = (const float*)d_in[0];
    const float* x_init = (const float*)d_in[1];
    const float* Jinv   = (const float*)d_in[2];
    const float* tfs    = (const float*)d_in[3];
    const float* W0     = (const float*)d_in[4];
    const float* b0     = (const float*)d_in[5];
    const float* W1     = (const float*)d_in[6];
    const float* b1     = (const float*)d_in[7];
    const float* W2     = (const float*)d_in[8];
    const float* b2     = (const float*)d_in[9];
    float* out = (float*)d_out;

    const int N = in_sizes[0] / 3;
    dim3 block(256);
    dim3 grid((N + 255) / 256);

    if (ws_size >= (size_t)(HDIM * NBLEND * sizeof(float))) {
        float* W2T = (float*)d_ws;
        hipLaunchKernelGGL(transpose_w2_kernel, dim3((HDIM * NBLEND + 255) / 256),
                           dim3(256), 0, stream, W2, W2T);
        hipLaunchKernelGGL((broyden_kernel<true>), grid, block, 0, stream,
                           xd, x_init, Jinv, tfs, W0, b0, W1, b1, W2T, b2, out, N);
    } else {
        hipLaunchKernelGGL((broyden_kernel<false>), grid, block, 0, stream,
                           xd, x_init, Jinv, tfs, W0, b0, W1, b1, W2, b2, out, N);
    }
}